// Round 4
// baseline (94.613 us; speedup 1.0000x reference)
//
#include <hip/hip_runtime.h>
#include <hip/hip_bf16.h>

#define HH 512
#define WW 640
#define HW (HH*WW)
#define NT 256
#define IMPIX 468              // 36 x 13 img halo pixels
#define IMPLANE (IMPIX*8)      // shorts per img channel-plane
#define H1PLANE (360*8)        // shorts per h1 channel-plane (36 x 10 pixels)

typedef short short8  __attribute__((ext_vector_type(8)));
typedef short short4v __attribute__((ext_vector_type(4)));
typedef float f32x16  __attribute__((ext_vector_type(16)));
typedef float f32x4   __attribute__((ext_vector_type(4)));

__device__ inline short f2bf(float f) {
    __hip_bfloat16 h = __float2bfloat16(f);
    short s; __builtin_memcpy(&s, &h, 2);
    return s;
}

// ---------------- prep: fold BN into w1, transpose weights to MFMA layouts ----------------
__global__ void prep_weights(const float* __restrict__ w1, const float* __restrict__ b1,
                             const float* __restrict__ gamma, const float* __restrict__ beta,
                             const float* __restrict__ rmean, const float* __restrict__ rvar,
                             const float* __restrict__ w2,
                             short* __restrict__ ws_w1, short* __restrict__ ws_w2,
                             float* __restrict__ ws_bias)
{
    int tid = blockIdx.x*blockDim.x + threadIdx.x;
    int stride = gridDim.x*blockDim.x;
    for (int i = tid; i < 4608; i += stride) {          // w1: [oc][c][t] -> [t][oc32][c16] * A_oc
        int oc = i / 144, rem = i - oc*144, c = rem / 9, t = rem - c*9;
        float a = gamma[oc] * rsqrtf(rvar[oc] + 1e-5f);
        ws_w1[t*512 + oc*16 + c] = f2bf(w1[i] * a);
    }
    for (int i = tid; i < 4608; i += stride) {          // w2: [f][c][t] -> [t][f16][c32], f>=9 zero
        int t = i >> 9, f = (i >> 5) & 15, c = i & 31;
        float val = (f < 9) ? w2[(f*32 + c)*9 + t] : 0.f;
        ws_w2[i] = f2bf(val);
    }
    if (tid < 32) {
        float a = gamma[tid] * rsqrtf(rvar[tid] + 1e-5f);
        ws_bias[tid] = beta[tid] + (b1[tid] - rmean[tid]) * a;
    }
}

// ---------------- main fused kernel ----------------
__launch_bounds__(NT, 4)
__global__ void fastprop_main(const float* __restrict__ depth,
                              const float* __restrict__ img,
                              const short* __restrict__ ws_w1,
                              const short* __restrict__ ws_w2,
                              const float* __restrict__ ws_bias,
                              float* __restrict__ out)
{
    __shared__ short s_img[2*IMPLANE];   // [ch/8 plane][pix 36x13][8ch] (14976 B)
    __shared__ short s_h1 [4*H1PLANE];   // [ch/8 plane][pix 36x10][8ch] (23040 B)
    __shared__ float s_depth[340];       // 34x10 replicate-clamped fp32 (1360 B)

    const int tid = threadIdx.x;

    // XCD-contiguous bijective remap: 5120 blocks = 8 XCDs x 640
    int nid = blockIdx.x;
    int oid = (nid & 7)*640 + (nid >> 3);
    int bz = oid / 1280; int rem = oid - bz*1280;
    int by = rem / 20;   int bx = rem - by*20;
    const int gy0 = by*8, gx0 = bx*32;

    const float* imgb = img   + (size_t)bz*16*HW;
    const float* dpb  = depth + (size_t)bz*HW;

    const int lane = tid & 63;
    const int wid  = tid >> 6;

    // conv1 A-fragments + bias from ws (L2/L3-resident per-lane b128 loads)
    const int oc = lane & 31, cg = lane >> 5;
    short8 a1[9];
    #pragma unroll
    for (int t = 0; t < 9; ++t)
        a1[t] = *(const short8*)&ws_w1[t*512 + oc*16 + cg*8];
    float bias_r[16];
    #pragma unroll
    for (int r = 0; r < 16; ++r)
        bias_r[r] = ws_bias[(r & 3) + 8*(r >> 2) + 4*cg];

    // ---- stage img tile (36x13 halo, zero at image OOB) + depth tile ----
    for (int idx = tid; idx < IMPIX; idx += NT) {
        int iy = idx / 36, ix = idx - iy*36;
        int gy = gy0 + iy - 2, gx = gx0 + ix - 2;
        bool v = ((unsigned)gy < HH) && ((unsigned)gx < WW);
        int cy = min(max(gy, 0), HH-1), cx = min(max(gx, 0), WW-1);
        const float* p = imgb + cy*WW + cx;
        short8 v0, v1;
        #pragma unroll
        for (int c = 0; c < 8; ++c)  v0[c] = v ? f2bf(p[c*HW]) : (short)0;
        #pragma unroll
        for (int c = 0; c < 8; ++c)  v1[c] = v ? f2bf(p[(c+8)*HW]) : (short)0;
        *(short8*)&s_img[idx*8]           = v0;   // plane 0: ch 0-7
        *(short8*)&s_img[IMPLANE + idx*8] = v1;   // plane 1: ch 8-15
    }
    for (int idx = tid; idx < 340; idx += NT) {
        int ty = idx / 34, tx = idx - ty*34;
        int gy = min(max(gy0 + ty - 1, 0), HH-1);
        int gx = min(max(gx0 + tx - 1, 0), WW-1);
        s_depth[idx] = dpb[gy*WW + gx];
    }
    __syncthreads();

    // ---- conv1 (32x32x16 MFMA, 9 taps) -> s_h1 ----
    {
        // tap pixel deltas {0,1,2,36,37,38,72,73,74} * 8 shorts
        const int OFS1[9] = {0, 8, 16, 288, 296, 304, 576, 584, 592};

        for (int g = wid; g < 12; g += 4) {
            int hp   = g*32 + (lane & 31);
            int base = cg*IMPLANE + hp*8;
            f32x16 accA, accB;
            #pragma unroll
            for (int i = 0; i < 16; ++i) { accA[i] = 0.f; accB[i] = 0.f; }
            __builtin_amdgcn_s_setprio(1);
            #pragma unroll
            for (int t = 0; t < 9; t += 2)
                accA = __builtin_amdgcn_mfma_f32_32x32x16_bf16(
                         a1[t], *(const short8*)&s_img[base + OFS1[t]], accA, 0, 0, 0);
            #pragma unroll
            for (int t = 1; t < 9; t += 2)
                accB = __builtin_amdgcn_mfma_f32_32x32x16_bf16(
                         a1[t], *(const short8*)&s_img[base + OFS1[t]], accB, 0, 0, 0);
            __builtin_amdgcn_s_setprio(0);
            f32x16 acc = accA + accB;

            if (hp < 360) {
                unsigned hy = (unsigned)hp / 36u;
                int hx = hp - (int)hy*36;
                int gy = gy0 + (int)hy - 1, gx = gx0 + hx - 1;
                bool inb = ((unsigned)gy < HH) && ((unsigned)gx < WW);
                #pragma unroll
                for (int q = 0; q < 4; ++q) {            // channels 8q + 4cg + 0..3 -> plane q
                    short4v h;
                    #pragma unroll
                    for (int j = 0; j < 4; ++j) {
                        float hv = fmaxf(acc[q*4 + j] + bias_r[q*4 + j], 0.f);
                        h[j] = inb ? f2bf(hv) : (short)0;
                    }
                    *(short4v*)&s_h1[q*H1PLANE + hp*8 + 4*cg] = h;
                }
            }
        }
    }
    __syncthreads();

    // ---- conv2 (16x16x32 MFMA, 9 taps) + softmax + depth gather ----
    {
        const int fl = lane & 15, cg2 = lane >> 4;
        short8 a2[9];
        #pragma unroll
        for (int t = 0; t < 9; ++t)
            a2[t] = *(const short8*)&ws_w2[t*512 + fl*32 + cg2*8];

        // tap pixel deltas {-37,-36,-35,-1,0,1,35,36,37} * 8 shorts
        const int OFS2[9] = {-296, -288, -280, -8, 0, 8, 280, 288, 296};

        for (int g = wid; g < 16; g += 4) {
            int po = g*16 + fl;
            int oy = po >> 5, ox = po & 31;
            int hbase = cg2*H1PLANE + ((oy + 1)*36 + (ox + 1))*8;
            f32x4 accA, accB;
            #pragma unroll
            for (int i = 0; i < 4; ++i) { accA[i] = 0.f; accB[i] = 0.f; }
            __builtin_amdgcn_s_setprio(1);
            #pragma unroll
            for (int t = 0; t < 9; t += 2)
                accA = __builtin_amdgcn_mfma_f32_16x16x32_bf16(
                         a2[t], *(const short8*)&s_h1[hbase + OFS2[t]], accA, 0, 0, 0);
            #pragma unroll
            for (int t = 1; t < 9; t += 2)
                accB = __builtin_amdgcn_mfma_f32_16x16x32_bf16(
                         a2[t], *(const short8*)&s_h1[hbase + OFS2[t]], accB, 0, 0, 0);
            __builtin_amdgcn_s_setprio(0);
            f32x4 lg = accA + accB;

            float num = 0.f, den = 0.f;
            #pragma unroll
            for (int r = 0; r < 4; ++r) {
                int f = cg2*4 + r;                 // conv2 output channel
                if (f < 9) {
                    float e = __expf(lg[r]);
                    int fy = f/3, fx = f - fy*3;   // tap (dy,dx) = (fy-1, fx-1)
                    float d = s_depth[(oy + fy)*34 + (ox + fx)];
                    den += e; num += e * d;
                }
            }
            num += __shfl_xor(num, 16); den += __shfl_xor(den, 16);
            num += __shfl_xor(num, 32); den += __shfl_xor(den, 32);
            if (cg2 == 0)
                out[(size_t)bz*HW + (size_t)(gy0 + oy)*WW + (gx0 + ox)] = num / den;
        }
    }
}

extern "C" void kernel_launch(void* const* d_in, const int* in_sizes, int n_in,
                              void* d_out, int out_size, void* d_ws, size_t ws_size,
                              hipStream_t stream) {
    const float* depth = (const float*)d_in[0];
    const float* img   = (const float*)d_in[1];
    const float* w1    = (const float*)d_in[2];
    const float* b1    = (const float*)d_in[3];
    const float* gamma = (const float*)d_in[4];
    const float* beta  = (const float*)d_in[5];
    const float* rmean = (const float*)d_in[6];
    const float* rvar  = (const float*)d_in[7];
    const float* w2    = (const float*)d_in[8];
    float* out = (float*)d_out;

    short* ws_w1   = (short*)d_ws;                       // 4608 shorts
    short* ws_w2   = ws_w1 + 4608;                       // 4608 shorts
    float* ws_bias = (float*)((char*)d_ws + 36864);      // 32 floats

    prep_weights<<<16, NT, 0, stream>>>(w1, b1, gamma, beta, rmean, rvar, w2,
                                        ws_w1, ws_w2, ws_bias);
    fastprop_main<<<5120, NT, 0, stream>>>(depth, img, ws_w1, ws_w2, ws_bias, out);
}

// Round 5
// 64.049 us; speedup vs baseline: 1.4772x; 1.4772x over previous
//
#include <hip/hip_runtime.h>
#include <hip/hip_bf16.h>

#define HH 512
#define WW 640
#define HW (HH*WW)
#define NT 256

typedef short short8  __attribute__((ext_vector_type(8)));
typedef short short4v __attribute__((ext_vector_type(4)));
typedef float f32x16  __attribute__((ext_vector_type(16)));
typedef float f32x4   __attribute__((ext_vector_type(4)));

__device__ inline short f2bf(float f) {
    __hip_bfloat16 h = __float2bfloat16(f);
    short s; __builtin_memcpy(&s, &h, 2);
    return s;
}

// ---- prep: fold BN into w1, bias as 10th tap row, transpose to MFMA layouts ----
__global__ void prep_weights(const float* __restrict__ w1, const float* __restrict__ b1,
                             const float* __restrict__ gamma, const float* __restrict__ beta,
                             const float* __restrict__ rmean, const float* __restrict__ rvar,
                             const float* __restrict__ w2,
                             short* __restrict__ ws_w1, short* __restrict__ ws_w2)
{
    int tid = blockIdx.x*blockDim.x + threadIdx.x;
    int stride = gridDim.x*blockDim.x;
    for (int i = tid; i < 4608; i += stride) {          // w1: [oc][c][t] -> [t][oc32][c16] * A_oc
        int oc = i / 144, rem = i - oc*144, c = rem / 9, t = rem - c*9;
        float a = gamma[oc] * rsqrtf(rvar[oc] + 1e-5f);
        ws_w1[t*512 + oc*16 + c] = f2bf(w1[i] * a);
    }
    for (int i = tid; i < 512; i += stride) {           // tap 9 = bias row (c==0 one-hot)
        int oc = i >> 4, c = i & 15;
        float a = gamma[oc] * rsqrtf(rvar[oc] + 1e-5f);
        float bias = beta[oc] + (b1[oc] - rmean[oc]) * a;
        ws_w1[9*512 + i] = (c == 0) ? f2bf(bias) : (short)0;
    }
    for (int i = tid; i < 4608; i += stride) {          // w2: [f][c][t] -> [t][f16][c32], f>=9 zero
        int t = i >> 9, f = (i >> 5) & 15, c = i & 31;
        float val = (f < 9) ? w2[(f*32 + c)*9 + t] : 0.f;
        ws_w2[i] = f2bf(val);
    }
}

// ---------------- main fused kernel ----------------
__launch_bounds__(NT, 4)
__global__ void fastprop_main(const float* __restrict__ depth,
                              const float* __restrict__ img,
                              const short* __restrict__ ws_w1,
                              const short* __restrict__ ws_w2,
                              float* __restrict__ out)
{
    __shared__ short s_img[468*16];   // [pix 36x13][16ch] bf16, 32B/pix
    __shared__ short s_h1 [360*32];   // [pix 36x10][32ch] bf16, 64B/pix
    __shared__ float s_depth[340];    // 34x10 replicate-clamped fp32

    const int tid = threadIdx.x;

    // XCD-contiguous bijective remap: 5120 blocks = 8 XCDs x 640
    int nid = blockIdx.x;
    int oid = (nid & 7)*640 + (nid >> 3);
    int bz = oid / 1280; int rem = oid - bz*1280;
    int by = rem / 20;   int bx = rem - by*20;
    const int gy0 = by*8, gx0 = bx*32;

    const float* imgb = img   + (size_t)bz*16*HW;
    const float* dpb  = depth + (size_t)bz*HW;

    const int lane = tid & 63;
    const int wid  = tid >> 6;

    // conv1 A-fragments (10 taps incl. bias row) from ws (L2-resident b128 loads)
    const int oc = lane & 31, cg = lane >> 5;
    short8 a1[10];
    #pragma unroll
    for (int t = 0; t < 10; ++t)
        a1[t] = *(const short8*)&ws_w1[t*512 + oc*16 + cg*8];
    short8 bb = (short8)0;                       // bias-tap B: one-hot 1.0 at k==0
    bb[0] = (cg == 0) ? (short)0x3F80 : (short)0;

    // ---- stage img tile (36x13 halo, zero at image OOB) + depth tile ----
    #pragma unroll
    for (int it = 0; it < 2; ++it) {
        int idx = tid + it*NT;
        if (idx < 468) {
            int iy = idx / 36, ix = idx - iy*36;
            int gy = gy0 + iy - 2, gx = gx0 + ix - 2;
            bool v = ((unsigned)gy < HH) && ((unsigned)gx < WW);
            int cy = min(max(gy, 0), HH-1), cx = min(max(gx, 0), WW-1);
            const float* p = imgb + cy*WW + cx;
            float m = v ? 1.f : 0.f;
            short8 v0, v1;
            #pragma unroll
            for (int c = 0; c < 8; ++c)  v0[c] = f2bf(m * p[c*HW]);
            #pragma unroll
            for (int c = 0; c < 8; ++c)  v1[c] = f2bf(m * p[(c+8)*HW]);
            *(short8*)&s_img[idx*16]     = v0;
            *(short8*)&s_img[idx*16 + 8] = v1;
        }
    }
    #pragma unroll
    for (int it = 0; it < 2; ++it) {
        int idx = tid + it*NT;
        if (idx < 340) {
            int ty = idx / 34, tx = idx - ty*34;
            int gy = min(max(gy0 + ty - 1, 0), HH-1);
            int gx = min(max(gx0 + tx - 1, 0), WW-1);
            s_depth[idx] = dpb[gy*WW + gx];
        }
    }
    __syncthreads();

    // ---- conv1 (32x32x16 MFMA, 9 taps + bias tap) -> s_h1 ----
    {
        // tap pixel deltas {0,1,2,36,37,38,72,73,74} * 16 shorts
        const int OFS1[9] = {0, 16, 32, 576, 592, 608, 1152, 1168, 1184};

        #pragma unroll
        for (int gi = 0; gi < 3; ++gi) {
            int g    = wid + gi*4;
            int hp   = g*32 + (lane & 31);
            int base = hp*16 + cg*8;
            f32x16 acc;
            #pragma unroll
            for (int i = 0; i < 16; ++i) acc[i] = 0.f;
            acc = __builtin_amdgcn_mfma_f32_32x32x16_bf16(a1[9], bb, acc, 0, 0, 0);
            #pragma unroll
            for (int t = 0; t < 9; ++t)
                acc = __builtin_amdgcn_mfma_f32_32x32x16_bf16(
                         a1[t], *(const short8*)&s_img[base + OFS1[t]], acc, 0, 0, 0);

            if (hp < 360) {
                unsigned hy = (unsigned)hp / 36u;
                int hx = hp - (int)hy*36;
                int gy = gy0 + (int)hy - 1, gx = gx0 + hx - 1;
                bool inb = ((unsigned)gy < HH) && ((unsigned)gx < WW);
                #pragma unroll
                for (int q = 0; q < 4; ++q) {            // channels 8q + 4cg + 0..3
                    short4v h;
                    #pragma unroll
                    for (int j = 0; j < 4; ++j) {
                        float hv = fmaxf(acc[q*4 + j], 0.f);
                        h[j] = inb ? f2bf(hv) : (short)0;
                    }
                    *(short4v*)&s_h1[hp*32 + 8*q + 4*cg] = h;
                }
            }
        }
    }
    __syncthreads();

    // ---- conv2 (16x16x32 MFMA, 9 taps) + softmax + depth gather ----
    {
        const int fl = lane & 15, cg2 = lane >> 4;
        short8 a2[9];
        #pragma unroll
        for (int t = 0; t < 9; ++t)
            a2[t] = *(const short8*)&ws_w2[t*512 + fl*32 + cg2*8];

        // tap pixel deltas {-37,-36,-35,-1,0,1,35,36,37} * 32 shorts
        const int OFS2[9] = {-1184, -1152, -1120, -32, 0, 32, 1120, 1152, 1184};

        #pragma unroll
        for (int gi = 0; gi < 4; ++gi) {
            int g  = wid + gi*4;
            int po = g*16 + fl;
            int oy = po >> 5, ox = po & 31;
            int hbase = ((oy + 1)*36 + (ox + 1))*32 + cg2*8;
            f32x4 acc;
            #pragma unroll
            for (int i = 0; i < 4; ++i) acc[i] = 0.f;
            #pragma unroll
            for (int t = 0; t < 9; ++t)
                acc = __builtin_amdgcn_mfma_f32_16x16x32_bf16(
                         a2[t], *(const short8*)&s_h1[hbase + OFS2[t]], acc, 0, 0, 0);

            float num = 0.f, den = 0.f;
            #pragma unroll
            for (int r = 0; r < 4; ++r) {
                int f = cg2*4 + r;                 // conv2 output channel
                if (f < 9) {
                    float e = __expf(acc[r]);
                    int fy = f/3, fx = f - fy*3;   // tap (dy,dx) = (fy-1, fx-1)
                    float d = s_depth[(oy + fy)*34 + (ox + fx)];
                    den += e; num += e * d;
                }
            }
            num += __shfl_xor(num, 16); den += __shfl_xor(den, 16);
            num += __shfl_xor(num, 32); den += __shfl_xor(den, 32);
            if (cg2 == 0)
                out[(size_t)bz*HW + (size_t)(gy0 + oy)*WW + (gx0 + ox)] = num / den;
        }
    }
}

extern "C" void kernel_launch(void* const* d_in, const int* in_sizes, int n_in,
                              void* d_out, int out_size, void* d_ws, size_t ws_size,
                              hipStream_t stream) {
    const float* depth = (const float*)d_in[0];
    const float* img   = (const float*)d_in[1];
    const float* w1    = (const float*)d_in[2];
    const float* b1    = (const float*)d_in[3];
    const float* gamma = (const float*)d_in[4];
    const float* beta  = (const float*)d_in[5];
    const float* rmean = (const float*)d_in[6];
    const float* rvar  = (const float*)d_in[7];
    const float* w2    = (const float*)d_in[8];
    float* out = (float*)d_out;

    short* ws_w1 = (short*)d_ws;          // 5120 shorts (10 taps x 512)
    short* ws_w2 = ws_w1 + 5120;          // 4608 shorts

    prep_weights<<<16, NT, 0, stream>>>(w1, b1, gamma, beta, rmean, rvar, w2,
                                        ws_w1, ws_w2);
    fastprop_main<<<5120, NT, 0, stream>>>(depth, img, ws_w1, ws_w2, out);
}

// Round 6
// 63.409 us; speedup vs baseline: 1.4921x; 1.0101x over previous
//
#include <hip/hip_runtime.h>
#include <hip/hip_bf16.h>

#define HH 512
#define WW 640
#define HW (HH*WW)
#define NT 256
#define IMPLANEP (468*8 + 8)    // img plane stride in shorts (+16B pad)
#define H1PLANEP (360*8 + 8)    // h1 plane stride in shorts (+16B pad)

typedef short short8  __attribute__((ext_vector_type(8)));
typedef short short4v __attribute__((ext_vector_type(4)));
typedef float f32x16  __attribute__((ext_vector_type(16)));
typedef float f32x4   __attribute__((ext_vector_type(4)));

__device__ inline short f2bf(float f) {
    __hip_bfloat16 h = __float2bfloat16(f);
    short s; __builtin_memcpy(&s, &h, 2);
    return s;
}

// ---- prep: fold BN into w1, bias as 10th tap row, transpose to MFMA layouts ----
__global__ void prep_weights(const float* __restrict__ w1, const float* __restrict__ b1,
                             const float* __restrict__ gamma, const float* __restrict__ beta,
                             const float* __restrict__ rmean, const float* __restrict__ rvar,
                             const float* __restrict__ w2,
                             short* __restrict__ ws_w1, short* __restrict__ ws_w2)
{
    int tid = blockIdx.x*blockDim.x + threadIdx.x;
    int stride = gridDim.x*blockDim.x;
    for (int i = tid; i < 4608; i += stride) {          // w1: [oc][c][t] -> [t][oc32][c16] * A_oc
        int oc = i / 144, rem = i - oc*144, c = rem / 9, t = rem - c*9;
        float a = gamma[oc] * rsqrtf(rvar[oc] + 1e-5f);
        ws_w1[t*512 + oc*16 + c] = f2bf(w1[i] * a);
    }
    for (int i = tid; i < 512; i += stride) {           // tap 9 = bias row (c==0 one-hot)
        int oc = i >> 4, c = i & 15;
        float a = gamma[oc] * rsqrtf(rvar[oc] + 1e-5f);
        float bias = beta[oc] + (b1[oc] - rmean[oc]) * a;
        ws_w1[9*512 + i] = (c == 0) ? f2bf(bias) : (short)0;
    }
    for (int i = tid; i < 4608; i += stride) {          // w2: [f][c][t] -> [t][f16][c32], f>=9 zero
        int t = i >> 9, f = (i >> 5) & 15, c = i & 31;
        float val = (f < 9) ? w2[(f*32 + c)*9 + t] : 0.f;
        ws_w2[i] = f2bf(val);
    }
}

// ---------------- main fused kernel ----------------
__launch_bounds__(NT, 4)
__global__ void fastprop_main(const float* __restrict__ depth,
                              const float* __restrict__ img,
                              const short* __restrict__ ws_w1,
                              const short* __restrict__ ws_w2,
                              float* __restrict__ out)
{
    __shared__ short s_img[2*IMPLANEP];   // [ch-plane][pix 36x13][8ch] bf16
    __shared__ short s_h1 [4*H1PLANEP];   // [ch-plane][pix 36x10][8ch] bf16
    __shared__ float s_depth[340];        // 34x10 replicate-clamped fp32

    const int tid = threadIdx.x;

    // XCD-contiguous bijective remap: 5120 blocks = 8 XCDs x 640
    int nid = blockIdx.x;
    int oid = (nid & 7)*640 + (nid >> 3);
    int bz = oid / 1280; int rem = oid - bz*1280;
    int by = rem / 20;   int bx = rem - by*20;
    const int gy0 = by*8, gx0 = bx*32;

    const float* imgb = img   + (size_t)bz*16*HW;
    const float* dpb  = depth + (size_t)bz*HW;

    const int lane = tid & 63;
    const int wid  = tid >> 6;

    // conv1 A-fragments (10 taps incl. bias row) from ws (L2-resident b128 loads)
    const int oc = lane & 31, cg = lane >> 5;
    short8 a1[10];
    #pragma unroll
    for (int t = 0; t < 10; ++t)
        a1[t] = *(const short8*)&ws_w1[t*512 + oc*16 + cg*8];
    short8 bb = (short8)0;                       // bias-tap B: one-hot 1.0 at k==0
    bb[0] = (cg == 0) ? (short)0x3F80 : (short)0;

    // ---- stage img tile: one 16B granule (8ch of one pixel) per thread-iter ----
    for (int g = tid; g < 936; g += NT) {
        int pixel = g >> 1, half = g & 1;
        int iy = pixel / 36, ix = pixel - iy*36;
        int gy = gy0 + iy - 2, gx = gx0 + ix - 2;
        bool v = ((unsigned)gy < HH) && ((unsigned)gx < WW);
        int cy = min(max(gy, 0), HH-1), cx = min(max(gx, 0), WW-1);
        const float* p = imgb + (size_t)(half*8)*HW + cy*WW + cx;
        float m = v ? 1.f : 0.f;
        short8 vv;
        #pragma unroll
        for (int c = 0; c < 8; ++c) vv[c] = f2bf(m * p[c*HW]);
        *(short8*)&s_img[half*IMPLANEP + pixel*8] = vv;
    }
    #pragma unroll
    for (int it = 0; it < 2; ++it) {
        int idx = tid + it*NT;
        if (idx < 340) {
            int ty = idx / 34, tx = idx - ty*34;
            int gy = min(max(gy0 + ty - 1, 0), HH-1);
            int gx = min(max(gx0 + tx - 1, 0), WW-1);
            s_depth[idx] = dpb[gy*WW + gx];
        }
    }
    __syncthreads();

    // ---- conv1 (32x32x16 MFMA, 9 taps + bias tap) -> s_h1 channel-planes ----
    {
        // tap pixel deltas {0,1,2,36,37,38,72,73,74} * 8 shorts (within a plane)
        const int OFS1[9] = {0, 8, 16, 288, 296, 304, 576, 584, 592};
        const int px = lane & 31;

        #pragma unroll
        for (int gi = 0; gi < 3; ++gi) {
            int g    = wid + gi*4;
            int hp   = g*32 + px;
            int base = cg*IMPLANEP + hp*8;
            f32x16 acc;
            #pragma unroll
            for (int i = 0; i < 16; ++i) acc[i] = 0.f;
            acc = __builtin_amdgcn_mfma_f32_32x32x16_bf16(a1[9], bb, acc, 0, 0, 0);
            #pragma unroll
            for (int t = 0; t < 9; ++t)
                acc = __builtin_amdgcn_mfma_f32_32x32x16_bf16(
                         a1[t], *(const short8*)&s_img[base + OFS1[t]], acc, 0, 0, 0);

            if (hp < 360) {
                unsigned hy = (unsigned)hp / 36u;
                int hx = hp - (int)hy*36;
                int gy = gy0 + (int)hy - 1, gx = gx0 + hx - 1;
                bool inb = ((unsigned)gy < HH) && ((unsigned)gx < WW);
                #pragma unroll
                for (int q = 0; q < 4; ++q) {      // plane q = channels 8q..8q+7
                    short4v h;
                    #pragma unroll
                    for (int j = 0; j < 4; ++j) {
                        float hv = fmaxf(acc[q*4 + j], 0.f);
                        h[j] = inb ? f2bf(hv) : (short)0;
                    }
                    *(short4v*)&s_h1[q*H1PLANEP + hp*8 + 4*cg] = h;
                }
            }
        }
    }
    __syncthreads();

    // ---- conv2 (16x16x32 MFMA) row-pair sliding window + softmax + gather ----
    {
        const int fl = lane & 15, cg2 = lane >> 4;
        short8 a2[9];
        #pragma unroll
        for (int t = 0; t < 9; ++t)
            a2[t] = *(const short8*)&ws_w2[t*512 + fl*32 + cg2*8];

        const int r0 = 2*wid;                 // this wave's output rows r0, r0+1

        #pragma unroll
        for (int chh = 0; chh < 2; ++chh) {   // column halves 0-15, 16-31
            const int ox0 = chh*16;
            const int colbase = cg2*H1PLANEP + (ox0 + fl)*8;

            short8 F[4][3];                   // [h1 row r0+i][dx]
            #pragma unroll
            for (int i = 0; i < 3; ++i)
                #pragma unroll
                for (int dx = 0; dx < 3; ++dx)
                    F[i][dx] = *(const short8*)&s_h1[colbase + ((r0 + i)*36 + dx)*8];
            // prefetch 4th row (for second output row of the pair)
            #pragma unroll
            for (int dx = 0; dx < 3; ++dx)
                F[3][dx] = *(const short8*)&s_h1[colbase + ((r0 + 3)*36 + dx)*8];

            f32x4 acc0, acc1;
            #pragma unroll
            for (int i = 0; i < 4; ++i) { acc0[i] = 0.f; acc1[i] = 0.f; }
            #pragma unroll
            for (int ty = 0; ty < 3; ++ty)
                #pragma unroll
                for (int tx = 0; tx < 3; ++tx)
                    acc0 = __builtin_amdgcn_mfma_f32_16x16x32_bf16(
                             a2[ty*3 + tx], F[ty][tx], acc0, 0, 0, 0);
            #pragma unroll
            for (int ty = 0; ty < 3; ++ty)
                #pragma unroll
                for (int tx = 0; tx < 3; ++tx)
                    acc1 = __builtin_amdgcn_mfma_f32_16x16x32_bf16(
                             a2[ty*3 + tx], F[ty + 1][tx], acc1, 0, 0, 0);

            // epilogue for the two rows
            #pragma unroll
            for (int rr = 0; rr < 2; ++rr) {
                f32x4 lg = rr ? acc1 : acc0;
                int oy = r0 + rr, ox = ox0 + fl;
                float num = 0.f, den = 0.f;
                #pragma unroll
                for (int r = 0; r < 4; ++r) {
                    int f = cg2*4 + r;             // conv2 output channel
                    if (f < 9) {
                        float e = __expf(lg[r]);
                        int fy = f/3, fx = f - fy*3;
                        float d = s_depth[(oy + fy)*34 + (ox + fx)];
                        den += e; num += e * d;
                    }
                }
                num += __shfl_xor(num, 16); den += __shfl_xor(den, 16);
                num += __shfl_xor(num, 32); den += __shfl_xor(den, 32);
                if (cg2 == 0)
                    out[(size_t)bz*HW + (size_t)(gy0 + oy)*WW + (gx0 + ox)] = num / den;
            }
        }
    }
}

extern "C" void kernel_launch(void* const* d_in, const int* in_sizes, int n_in,
                              void* d_out, int out_size, void* d_ws, size_t ws_size,
                              hipStream_t stream) {
    const float* depth = (const float*)d_in[0];
    const float* img   = (const float*)d_in[1];
    const float* w1    = (const float*)d_in[2];
    const float* b1    = (const float*)d_in[3];
    const float* gamma = (const float*)d_in[4];
    const float* beta  = (const float*)d_in[5];
    const float* rmean = (const float*)d_in[6];
    const float* rvar  = (const float*)d_in[7];
    const float* w2    = (const float*)d_in[8];
    float* out = (float*)d_out;

    short* ws_w1 = (short*)d_ws;          // 5120 shorts (10 taps x 512)
    short* ws_w2 = ws_w1 + 5120;          // 4608 shorts

    prep_weights<<<16, NT, 0, stream>>>(w1, b1, gamma, beta, rmean, rvar, w2,
                                        ws_w1, ws_w2);
    fastprop_main<<<5120, NT, 0, stream>>>(depth, img, ws_w1, ws_w2, out);
}